// Round 8
// baseline (758.574 us; speedup 1.0000x reference)
//
#include <hip/hip_runtime.h>

#define DEVI __device__ __forceinline__

typedef __bf16 bf16x8 __attribute__((ext_vector_type(8)));
typedef float f32x4 __attribute__((ext_vector_type(4)));

// ---------- exact bf16 RNE helpers ----------
DEVI unsigned short f2bf(float f) {
  unsigned u = __float_as_uint(f);
  u = (u + 0x7FFFu + ((u >> 16) & 1u)) >> 16;
  return (unsigned short)u;
}
DEVI float bf2f(unsigned short h) { return __uint_as_float(((unsigned)h) << 16); }
DEVI float bf16r(float f) { return bf2f(f2bf(f)); }

// ---------- fast MXINT8 scale from block amax (amax normal, >0) ----------
DEVI void mx_scales(float amax, float& scale, float& inv) {
  unsigned eb = __float_as_uint(amax) & 0x7f800000u;
  scale = __uint_as_float(eb - (6u << 23));          // 2^(e-6)
  inv   = __uint_as_float((260u << 23) - eb);        // 2^(6-e)
}

DEVI unsigned short quantv(float v, float scale, float inv) {
  float qv = rintf(v * inv);                          // RNE, matches jnp.round
  qv = fminf(fmaxf(qv, -128.f), 127.f);
  return f2bf(qv * scale);                            // exact in bf16
}

DEVI void quant8(const float* h, float amax, unsigned short* q) {
  if (amax > 0.f) {
    float scale, inv;
    mx_scales(amax, scale, inv);
#pragma unroll
    for (int k = 0; k < 8; ++k) q[k] = quantv(h[k], scale, inv);
  } else {
#pragma unroll
    for (int k = 0; k < 8; ++k) q[k] = 0;
  }
}

// ---------- 16-lane (DPP row) max reduction on the VALU pipe ----------
template <int N>
DEVI float qmax_step(float x) {
  int y = __builtin_amdgcn_update_dpp(0, __float_as_int(x), 0x120 | N, 0xF, 0xF, true);
  return fmaxf(x, __int_as_float(y));
}
DEVI float quad_row_max(float x) {
  x = qmax_step<1>(x);
  x = qmax_step<2>(x);
  x = qmax_step<4>(x);
  x = qmax_step<8>(x);
  return x;
}

// ---------- async global->LDS 16B ----------
DEVI void gl2lds16(const void* g, void* l) {
  __builtin_amdgcn_global_load_lds(
      (__attribute__((address_space(1))) void*)const_cast<void*>(g),
      (__attribute__((address_space(3))) void*)l, 16, 0, 0);
}

DEVI uint4 pack8(const unsigned short* q) {
  uint4 o;
  o.x = (unsigned)q[0] | ((unsigned)q[1] << 16);
  o.y = (unsigned)q[2] | ((unsigned)q[3] << 16);
  o.z = (unsigned)q[4] | ((unsigned)q[5] << 16);
  o.w = (unsigned)q[6] | ((unsigned)q[7] << 16);
  return o;
}

// ---------- merged prep: W1 quant | W2 quant | LN+quant in ONE dispatch ----------
__global__ __launch_bounds__(256) void prep_k(const float* __restrict__ W1,
                                              const float* __restrict__ W2,
                                              const float* __restrict__ X,
                                              const float* __restrict__ lw,
                                              const float* __restrict__ lb,
                                              unsigned short* __restrict__ qW1,
                                              unsigned short* __restrict__ qW2,
                                              unsigned short* __restrict__ a1) {
  __shared__ float red[4];
  const int bid = blockIdx.x;
  const int t = threadIdx.x;
  if (bid < 16384) {
    const float* src = (bid < 8192) ? W1 : W2;
    unsigned short* dst = (bid < 8192) ? qW1 : qW2;
    size_t idx = (size_t)(bid & 8191) * 256 + t;   // 8 elems/thread
    float4 v0 = ((const float4*)src)[idx * 2];
    float4 v1 = ((const float4*)src)[idx * 2 + 1];
    float h[8] = {v0.x, v0.y, v0.z, v0.w, v1.x, v1.y, v1.z, v1.w};
    float amax = 0.f;
#pragma unroll
    for (int k = 0; k < 8; ++k) amax = fmaxf(amax, fabsf(h[k]));
    amax = fmaxf(amax, __shfl_xor(amax, 1));   // 4 consecutive lanes = one 32-block
    amax = fmaxf(amax, __shfl_xor(amax, 2));
    unsigned short q[8];
    quant8(h, amax, q);
    ((uint4*)dst)[idx] = pack8(q);
  } else {
    const int H = 2048;
    const int row = bid - 16384;
    const int lane = t & 63, wave = t >> 6;
    const float* xr = X + (size_t)row * H;
    float4 v0 = ((const float4*)xr)[2 * t];
    float4 v1 = ((const float4*)xr)[2 * t + 1];
    float x[8] = {bf16r(v0.x), bf16r(v0.y), bf16r(v0.z), bf16r(v0.w),
                  bf16r(v1.x), bf16r(v1.y), bf16r(v1.z), bf16r(v1.w)};
    float s = 0.f;
#pragma unroll
    for (int k = 0; k < 8; ++k) s += x[k];
#pragma unroll
    for (int o = 32; o; o >>= 1) s += __shfl_xor(s, o);
    if (lane == 0) red[wave] = s;
    __syncthreads();
    float mu = (red[0] + red[1] + red[2] + red[3]) * (1.0f / H);
    __syncthreads();
    float v = 0.f;
#pragma unroll
    for (int k = 0; k < 8; ++k) { float d = x[k] - mu; v += d * d; }
#pragma unroll
    for (int o = 32; o; o >>= 1) v += __shfl_xor(v, o);
    if (lane == 0) red[wave] = v;
    __syncthreads();
    float var = (red[0] + red[1] + red[2] + red[3]) * (1.0f / H);
    float rstd = 1.0f / sqrtf(var + 1e-5f);
    float h[8];
    float amax = 0.f;
#pragma unroll
    for (int k = 0; k < 8; ++k) {
      int col = t * 8 + k;
      h[k] = bf16r((x[k] - mu) * rstd * lw[col] + lb[col]);
      amax = fmaxf(amax, fabsf(h[k]));
    }
    amax = fmaxf(amax, __shfl_xor(amax, 1));
    amax = fmaxf(amax, __shfl_xor(amax, 2));
    unsigned short q[8];
    quant8(h, amax, q);
    ((uint4*)(a1 + (size_t)row * H))[t] = pack8(q);
  }
}

// ---------- GEMM: C[m,n] = sum_k A[m,k]*B[n,k], A/B bf16, fp32 acc ----------
// ROUND-0 STRUCTURE with B TAKEN OUT OF LDS (LDS pipe was the saturated
// resource: ~1030 cyc/K-tile/CU vs 620 MFMA; B-direct cuts LDS to ~515).
//  - 128x128 tile, BK=64, 4 waves, per-wave 64x64 (4x4 of 16x16x32 MFMA).
//  - A: staged via global_load_lds exactly as r0 (zero-conflict XOR swizzle:
//    chunk c of row r at LDS chunk c^(r&7); read chunk (s*4+quad)^(lr&7)).
//  - B: each lane global_load_dwordx4's its MFMA-ready fragment directly
//    (B[n][k] row-major: addr = (n0+wc+j*16+lr)*K + k0+s*32+quad*8 -- the
//    exact B-operand layout). Tile t+1's 8 B-frags are prefetched right
//    after the tile-t barrier so L2 latency hides under ds_read+MFMA; the
//    end-of-tile barrier's vmcnt(0) drain finds them complete.
//  - Barrier structure, MFMA order, epilogues: identical to r0 (bit-identical
//    numerics). Default grid order (r0's best-measured FETCH).
// MODE 1: h = bf16(gelu_tanh(bf16(y+bias))) then FUSED MX-quant along N via
//   DPP row max -> quantized bf16 [M,N]
// MODE 2: out = bf16(bf16(resid) + bf16(y + bias)) -> float [M,N]
template <int MODE>
__global__ __launch_bounds__(256) void gemm_mx(const unsigned short* __restrict__ A,
                                               const unsigned short* __restrict__ B,
                                               int M, int N, int K,
                                               const float* __restrict__ bias,
                                               const float* __restrict__ resid,
                                               void* __restrict__ outp) {
  __shared__ unsigned short As[128 * 64];   // 16 KiB (B no longer staged)

  const int tid = threadIdx.x;
  const int lane = tid & 63;
  const int wave = tid >> 6;
  const int wr = (wave >> 1) * 64;   // wave row offset in tile
  const int wc = (wave & 1) * 64;    // wave col offset in tile
  const int lr = lane & 15;
  const int quad = lane >> 4;

  const int m0 = blockIdx.y * 128;
  const int n0 = blockIdx.x * 128;

  // A staging: LDS unit n (fixed dest n*16 B) = row n>>3, LDS chunk n&7.
  // Source global chunk = (n&7) ^ (row&7)  [swizzle].  (identical to r0)
  size_t aoff[4];
  int lbase[4];
#pragma unroll
  for (int j = 0; j < 4; ++j) {
    int n = j * 256 + tid;
    int r = n >> 3, c = (n & 7) ^ (r & 7);
    aoff[j] = (size_t)(m0 + r) * K + (size_t)c * 8;
    lbase[j] = (j * 256 + (tid & ~63)) * 8;  // wave-uniform LDS base (ushort units)
  }

  // A fragment-read addressing (hoisted; row&7 == lr&7 since wr,i*16 = 0 mod 8)
  int arow[4];
#pragma unroll
  for (int i = 0; i < 4; ++i) arow[i] = (wr + i * 16 + lr) * 64;
  const int ch0 = (quad ^ (lr & 7)) * 8;        // s=0 chunk offset (ushorts)
  const int ch1 = ((4 + quad) ^ (lr & 7)) * 8;  // s=1

  // B direct-fragment base: lane's row = n0 + wc + j*16 + lr, k-chunk quad
  const unsigned short* bbase = B + (size_t)(n0 + wc + lr) * K + quad * 8;
  const int brstep = 16 * K;                    // j stride (ushorts)

  f32x4 acc[4][4];
#pragma unroll
  for (int i = 0; i < 4; ++i)
#pragma unroll
    for (int j = 0; j < 4; ++j) acc[i][j] = (f32x4){0.f, 0.f, 0.f, 0.f};

  const int NT = K >> 6;

  bf16x8 bX0[4], bX1[4], bY0[4], bY1[4];
  // prologue: tile 0's B fragments
#pragma unroll
  for (int j = 0; j < 4; ++j) {
    bX0[j] = *(const bf16x8*)(bbase + j * brstep);
    bX1[j] = *(const bf16x8*)(bbase + j * brstep + 32);
  }

#define G_TILE(T, BC0, BC1, BN0, BN1)                                           \
  {                                                                             \
    const int k0_ = (T) * 64;                                                   \
    _Pragma("unroll")                                                           \
    for (int j = 0; j < 4; ++j) gl2lds16(A + aoff[j] + k0_, As + lbase[j]);     \
    __syncthreads(); /* A(T) visible */                                         \
    if ((T) + 1 < NT) { /* prefetch B(T+1); hides under ds_read+MFMA */         \
      _Pragma("unroll")                                                         \
      for (int j = 0; j < 4; ++j) {                                             \
        BN0[j] = *(const bf16x8*)(bbase + j * brstep + k0_ + 64);               \
        BN1[j] = *(const bf16x8*)(bbase + j * brstep + k0_ + 96);               \
      }                                                                         \
    }                                                                           \
    bf16x8 af[4];                                                               \
    _Pragma("unroll")                                                           \
    for (int i = 0; i < 4; ++i) af[i] = *(const bf16x8*)(As + arow[i] + ch0);   \
    _Pragma("unroll")                                                           \
    for (int i = 0; i < 4; ++i)                                                 \
      _Pragma("unroll")                                                         \
      for (int j = 0; j < 4; ++j)                                               \
        acc[i][j] = __builtin_amdgcn_mfma_f32_16x16x32_bf16(af[i], BC0[j], acc[i][j], 0, 0, 0); \
    _Pragma("unroll")                                                           \
    for (int i = 0; i < 4; ++i) af[i] = *(const bf16x8*)(As + arow[i] + ch1);   \
    _Pragma("unroll")                                                           \
    for (int i = 0; i < 4; ++i)                                                 \
      _Pragma("unroll")                                                         \
      for (int j = 0; j < 4; ++j)                                               \
        acc[i][j] = __builtin_amdgcn_mfma_f32_16x16x32_bf16(af[i], BC1[j], acc[i][j], 0, 0, 0); \
    __syncthreads(); /* A reads done before next stage; drains B prefetch */    \
  }

  for (int t = 0; t < NT; t += 2) {
    G_TILE(t, bX0, bX1, bY0, bY1);
    G_TILE(t + 1, bY0, bY1, bX0, bX1);
  }
#undef G_TILE

  // epilogue: D mapping col = lane&15, row = quad*4 + reg   [m89-verified]
  if (MODE == 1) {
#pragma unroll
    for (int i = 0; i < 4; ++i) {
#pragma unroll
      for (int r = 0; r < 4; ++r) {
        const int gm = m0 + wr + i * 16 + quad * 4 + r;
        float g[4];
#pragma unroll
        for (int j = 0; j < 4; ++j) {
          float t = bf16r(acc[i][j][r] + bias[n0 + wc + j * 16 + lr]);
          float u = 0.7978845608028654f * (t + 0.044715f * t * t * t);
          g[j] = bf16r(0.5f * t * (1.0f + tanhf(u)));
        }
        // fused MX quant: 32-col block = {j0,j1} / {j2,j3} over this quad's lanes
        float a = quad_row_max(fmaxf(fabsf(g[0]), fabsf(g[1])));
        float b = quad_row_max(fmaxf(fabsf(g[2]), fabsf(g[3])));
        unsigned short q[4];
        if (a > 0.f) {
          float sc, iv; mx_scales(a, sc, iv);
          q[0] = quantv(g[0], sc, iv); q[1] = quantv(g[1], sc, iv);
        } else { q[0] = q[1] = 0; }
        if (b > 0.f) {
          float sc, iv; mx_scales(b, sc, iv);
          q[2] = quantv(g[2], sc, iv); q[3] = quantv(g[3], sc, iv);
        } else { q[2] = q[3] = 0; }
        unsigned short* orow = (unsigned short*)outp + (size_t)gm * N + n0 + wc + lr;
#pragma unroll
        for (int j = 0; j < 4; ++j) orow[j * 16] = q[j];
      }
    }
  } else {
#pragma unroll
    for (int i = 0; i < 4; ++i) {
#pragma unroll
      for (int j = 0; j < 4; ++j) {
#pragma unroll
        for (int r = 0; r < 4; ++r) {
          int gm = m0 + wr + i * 16 + quad * 4 + r;
          int gn = n0 + wc + j * 16 + lr;
          float h = bf16r(acc[i][j][r] + bias[gn]);
          float rr = bf16r(resid[(size_t)gm * N + gn]);
          ((float*)outp)[(size_t)gm * N + gn] = bf16r(rr + h);
        }
      }
    }
  }
  (void)M;
}

extern "C" void kernel_launch(void* const* d_in, const int* in_sizes, int n_in,
                              void* d_out, int out_size, void* d_ws, size_t ws_size,
                              hipStream_t stream) {
  const float* inputs = (const float*)d_in[0];  // [2,2048,2048]
  const float* ln_w   = (const float*)d_in[1];  // [2048]
  const float* ln_b   = (const float*)d_in[2];  // [2048]
  const float* W1     = (const float*)d_in[3];  // [8192,2048]
  const float* b1     = (const float*)d_in[4];  // [8192]
  const float* W2     = (const float*)d_in[5];  // [2048,8192]
  const float* b2     = (const float*)d_in[6];  // [2048]
  float* out = (float*)d_out;                   // [2,2048,2048] fp32 (bf16-valued)
  char* ws = (char*)d_ws;
  (void)in_sizes; (void)n_in; (void)out_size; (void)ws_size;

  // workspace layout (144 MiB total)
  unsigned short* qW1  = (unsigned short*)(ws);                      // 32 MiB
  unsigned short* qW2  = (unsigned short*)(ws + (size_t)33554432);   // 32 MiB
  unsigned short* a1   = (unsigned short*)(ws + (size_t)67108864);   // 16 MiB [4096,2048]
  unsigned short* act2 = (unsigned short*)(ws + (size_t)83886080);   // 64 MiB [4096,8192]

  const int M = 4096;

  // 1. merged prep: quantize W1+W2 and LN+quant the activations (one dispatch)
  prep_k<<<20480, 256, 0, stream>>>(W1, W2, inputs, ln_w, ln_b, qW1, qW2, a1);

  // 2. GEMM1 + bias + gelu + fused MX quant (DPP) -> quantized bf16 [4096,8192]
  gemm_mx<1><<<dim3(8192 / 128, M / 128), 256, 0, stream>>>(
      a1, qW1, M, 8192, 2048, b1, nullptr, (void*)act2);

  // 3. GEMM2 [4096,8192] x [2048,8192]^T + bias + residual -> fp32 out
  gemm_mx<2><<<dim3(2048 / 128, M / 128), 256, 0, stream>>>(
      act2, qW2, M, 2048, 8192, b2, inputs, (void*)out);
}

// Round 9
// 504.097 us; speedup vs baseline: 1.5048x; 1.5048x over previous
//
#include <hip/hip_runtime.h>

#define DEVI __device__ __forceinline__

typedef __bf16 bf16x8 __attribute__((ext_vector_type(8)));
typedef float f32x4 __attribute__((ext_vector_type(4)));

// ---------- exact bf16 RNE helpers ----------
DEVI unsigned short f2bf(float f) {
  unsigned u = __float_as_uint(f);
  u = (u + 0x7FFFu + ((u >> 16) & 1u)) >> 16;
  return (unsigned short)u;
}
DEVI float bf2f(unsigned short h) { return __uint_as_float(((unsigned)h) << 16); }
DEVI float bf16r(float f) { return bf2f(f2bf(f)); }

// ---------- fast MXINT8 scale from block amax (amax normal, >0) ----------
// shared_exp = floor(log2(amax)) = exponent field - 127 (bit extract, no libm).
DEVI void mx_scales(float amax, float& scale, float& inv) {
  unsigned eb = __float_as_uint(amax) & 0x7f800000u;
  scale = __uint_as_float(eb - (6u << 23));          // 2^(e-6)
  inv   = __uint_as_float((260u << 23) - eb);        // 2^(6-e)
}

DEVI unsigned short quantv(float v, float scale, float inv) {
  float qv = rintf(v * inv);                          // RNE, matches jnp.round
  qv = fminf(fmaxf(qv, -128.f), 127.f);
  return f2bf(qv * scale);                            // exact in bf16
}

DEVI void quant8(const float* h, float amax, unsigned short* q) {
  if (amax > 0.f) {
    float scale, inv;
    mx_scales(amax, scale, inv);
#pragma unroll
    for (int k = 0; k < 8; ++k) q[k] = quantv(h[k], scale, inv);
  } else {
#pragma unroll
    for (int k = 0; k < 8; ++k) q[k] = 0;
  }
}

// ---------- 16-lane (DPP row) max reduction on the VALU pipe ----------
template <int N>
DEVI float qmax_step(float x) {
  int y = __builtin_amdgcn_update_dpp(0, __float_as_int(x), 0x120 | N, 0xF, 0xF, true);
  return fmaxf(x, __int_as_float(y));
}
DEVI float quad_row_max(float x) {
  x = qmax_step<1>(x);
  x = qmax_step<2>(x);
  x = qmax_step<4>(x);
  x = qmax_step<8>(x);
  return x;
}

// ---------- async global->LDS 16B ----------
DEVI void gl2lds16(const void* g, void* l) {
  __builtin_amdgcn_global_load_lds(
      (__attribute__((address_space(1))) void*)const_cast<void*>(g),
      (__attribute__((address_space(3))) void*)l, 16, 0, 0);
}

DEVI uint4 pack8(const unsigned short* q) {
  uint4 o;
  o.x = (unsigned)q[0] | ((unsigned)q[1] << 16);
  o.y = (unsigned)q[2] | ((unsigned)q[3] << 16);
  o.z = (unsigned)q[4] | ((unsigned)q[5] << 16);
  o.w = (unsigned)q[6] | ((unsigned)q[7] << 16);
  return o;
}

// ---------- one 8-elem MX group: load, quant, store ----------
DEVI void wgroup(const float* __restrict__ src, unsigned short* __restrict__ dst,
                 size_t gi) {
  float4 v0 = ((const float4*)src)[gi * 2];
  float4 v1 = ((const float4*)src)[gi * 2 + 1];
  float h[8] = {v0.x, v0.y, v0.z, v0.w, v1.x, v1.y, v1.z, v1.w};
  float amax = 0.f;
#pragma unroll
  for (int k = 0; k < 8; ++k) amax = fmaxf(amax, fabsf(h[k]));
  amax = fmaxf(amax, __shfl_xor(amax, 1));   // 4 consecutive lanes = one 32-block
  amax = fmaxf(amax, __shfl_xor(amax, 2));
  unsigned short q[8];
  quant8(h, amax, q);
  ((uint4*)dst)[gi] = pack8(q);
}

// ---------- merged prep: W1 quant | W2 quant | LN+quant, 512-thr blocks ----------
// blocks [0,2048): W1 ; [2048,4096): W2 ; [4096,6144): LN (2 rows/block).
// Weight blocks: 512 thr x 2 independent 8-elem groups (4 loads in flight,
// 8192 elems/block) -- 3.3x fewer blocks than r0's prep, same arithmetic.
// LN blocks: waves 0-3 = row 2r, waves 4-7 = row 2r+1; per-half reductions.
__global__ __launch_bounds__(512) void prep_k(const float* __restrict__ W1,
                                              const float* __restrict__ W2,
                                              const float* __restrict__ X,
                                              const float* __restrict__ lw,
                                              const float* __restrict__ lb,
                                              unsigned short* __restrict__ qW1,
                                              unsigned short* __restrict__ qW2,
                                              unsigned short* __restrict__ a1) {
  __shared__ float red[8];
  const int bid = blockIdx.x;
  const int t = threadIdx.x;
  if (bid < 4096) {
    const float* src = (bid < 2048) ? W1 : W2;
    unsigned short* dst = (bid < 2048) ? qW1 : qW2;
    const size_t g0 = (size_t)(bid & 2047) * 1024 + t;   // group = 8 elems
    wgroup(src, dst, g0);
    wgroup(src, dst, g0 + 512);
  } else {
    const int H = 2048;
    const int t8 = t & 255;
    const int row = (bid - 4096) * 2 + (t >> 8);
    const int lane = t & 63, wave = t >> 6;      // wave 0..7
    const int wbase = (wave & 4);                // 0 for row-half 0, 4 for half 1
    const float* xr = X + (size_t)row * H;
    float4 v0 = ((const float4*)xr)[2 * t8];
    float4 v1 = ((const float4*)xr)[2 * t8 + 1];
    float x[8] = {bf16r(v0.x), bf16r(v0.y), bf16r(v0.z), bf16r(v0.w),
                  bf16r(v1.x), bf16r(v1.y), bf16r(v1.z), bf16r(v1.w)};
    float s = 0.f;
#pragma unroll
    for (int k = 0; k < 8; ++k) s += x[k];
#pragma unroll
    for (int o = 32; o; o >>= 1) s += __shfl_xor(s, o);
    if (lane == 0) red[wave] = s;
    __syncthreads();
    float mu = (red[wbase] + red[wbase + 1] + red[wbase + 2] + red[wbase + 3]) * (1.0f / H);
    __syncthreads();
    float v = 0.f;
#pragma unroll
    for (int k = 0; k < 8; ++k) { float d = x[k] - mu; v += d * d; }
#pragma unroll
    for (int o = 32; o; o >>= 1) v += __shfl_xor(v, o);
    if (lane == 0) red[wave] = v;
    __syncthreads();
    float var = (red[wbase] + red[wbase + 1] + red[wbase + 2] + red[wbase + 3]) * (1.0f / H);
    float rstd = 1.0f / sqrtf(var + 1e-5f);
    float h[8];
    float amax = 0.f;
#pragma unroll
    for (int k = 0; k < 8; ++k) {
      int col = t8 * 8 + k;
      h[k] = bf16r((x[k] - mu) * rstd * lw[col] + lb[col]);
      amax = fmaxf(amax, fabsf(h[k]));
    }
    amax = fmaxf(amax, __shfl_xor(amax, 1));
    amax = fmaxf(amax, __shfl_xor(amax, 2));
    unsigned short q[8];
    quant8(h, amax, q);
    ((uint4*)(a1 + (size_t)row * H))[t8] = pack8(q);
  }
}

// ---------- GEMM: C[m,n] = sum_k A[m,k]*B[n,k], A/B bf16, fp32 acc ----------
// ROUND-0 KERNEL, byte-identical (measured best across 8 rounds: 187.7us,
// 0 bank conflicts, MfmaUtil 33%). All alternatives falsified: phase-split
// schedules (r1-r5, 25-31% MfmaUtil), 32x32 MFMA (r6, conflicts), XCD
// swizzle (r7, +fetch no speedup), B-direct-from-L2 (r8, 1.7x slower).
// 128x128 tile, BK=64, 4 waves, each wave 64x64 (4x4 of 16x16x32 MFMA).
// LDS XOR-swizzle: chunk c of row r at LDS chunk c^(r&7) (conflicts 5e7->0).
// MODE 1: h = bf16(gelu_tanh(bf16(y+bias))) then FUSED MX-quant along N via
//   DPP row max -> quantized bf16 [M,N]
// MODE 2: out = bf16(bf16(resid) + bf16(y + bias)) -> float [M,N]
template <int MODE>
__global__ __launch_bounds__(256) void gemm_mx(const unsigned short* __restrict__ A,
                                               const unsigned short* __restrict__ B,
                                               int M, int N, int K,
                                               const float* __restrict__ bias,
                                               const float* __restrict__ resid,
                                               void* __restrict__ outp) {
  __shared__ unsigned short As[128 * 64];
  __shared__ unsigned short Bs[128 * 64];

  const int tid = threadIdx.x;
  const int lane = tid & 63;
  const int wave = tid >> 6;
  const int wr = (wave >> 1) * 64;   // wave row offset in tile
  const int wc = (wave & 1) * 64;    // wave col offset in tile
  const int lr = lane & 15;
  const int quad = lane >> 4;

  const int m0 = blockIdx.y * 128;
  const int n0 = blockIdx.x * 128;

  // staging: LDS unit n (fixed dest n*16 B) = row n>>3, LDS chunk n&7.
  // Source global chunk = (n&7) ^ (row&7)  [swizzle].
  size_t aoff[4], boff[4];
  int lbase[4];
#pragma unroll
  for (int j = 0; j < 4; ++j) {
    int n = j * 256 + tid;
    int r = n >> 3, c = (n & 7) ^ (r & 7);
    aoff[j] = (size_t)(m0 + r) * K + (size_t)c * 8;
    boff[j] = (size_t)(n0 + r) * K + (size_t)c * 8;
    lbase[j] = (j * 256 + (tid & ~63)) * 8;  // wave-uniform LDS base (ushort units)
  }

  f32x4 acc[4][4];
#pragma unroll
  for (int i = 0; i < 4; ++i)
#pragma unroll
    for (int j = 0; j < 4; ++j) acc[i][j] = (f32x4){0.f, 0.f, 0.f, 0.f};

  for (int k0 = 0; k0 < K; k0 += 64) {
#pragma unroll
    for (int j = 0; j < 4; ++j) gl2lds16(A + aoff[j] + k0, As + lbase[j]);
#pragma unroll
    for (int j = 0; j < 4; ++j) gl2lds16(B + boff[j] + k0, Bs + lbase[j]);
    __syncthreads();  // drains vmcnt -> LDS tiles visible
#pragma unroll
    for (int s = 0; s < 2; ++s) {
      bf16x8 af[4], bfr[4];
#pragma unroll
      for (int i = 0; i < 4; ++i) {
        int row = wr + i * 16 + lr;
        int ch = (s * 4 + quad) ^ (row & 7);
        af[i] = *(const bf16x8*)(As + row * 64 + ch * 8);
      }
#pragma unroll
      for (int j = 0; j < 4; ++j) {
        int row = wc + j * 16 + lr;
        int ch = (s * 4 + quad) ^ (row & 7);
        bfr[j] = *(const bf16x8*)(Bs + row * 64 + ch * 8);
      }
#pragma unroll
      for (int i = 0; i < 4; ++i)
#pragma unroll
        for (int j = 0; j < 4; ++j)
          acc[i][j] = __builtin_amdgcn_mfma_f32_16x16x32_bf16(af[i], bfr[j], acc[i][j], 0, 0, 0);
    }
    __syncthreads();  // all reads done before next stage overwrites
  }

  // epilogue: D mapping col = lane&15, row = quad*4 + reg   [m89-verified]
  if (MODE == 1) {
#pragma unroll
    for (int i = 0; i < 4; ++i) {
#pragma unroll
      for (int r = 0; r < 4; ++r) {
        const int gm = m0 + wr + i * 16 + quad * 4 + r;
        float g[4];
#pragma unroll
        for (int j = 0; j < 4; ++j) {
          float t = bf16r(acc[i][j][r] + bias[n0 + wc + j * 16 + lr]);
          float u = 0.7978845608028654f * (t + 0.044715f * t * t * t);
          g[j] = bf16r(0.5f * t * (1.0f + tanhf(u)));
        }
        // fused MX quant: 32-col block = {j0,j1} / {j2,j3} over this quad's lanes
        float a = quad_row_max(fmaxf(fabsf(g[0]), fabsf(g[1])));
        float b = quad_row_max(fmaxf(fabsf(g[2]), fabsf(g[3])));
        unsigned short q[4];
        if (a > 0.f) {
          float sc, iv; mx_scales(a, sc, iv);
          q[0] = quantv(g[0], sc, iv); q[1] = quantv(g[1], sc, iv);
        } else { q[0] = q[1] = 0; }
        if (b > 0.f) {
          float sc, iv; mx_scales(b, sc, iv);
          q[2] = quantv(g[2], sc, iv); q[3] = quantv(g[3], sc, iv);
        } else { q[2] = q[3] = 0; }
        unsigned short* orow = (unsigned short*)outp + (size_t)gm * N + n0 + wc + lr;
#pragma unroll
        for (int j = 0; j < 4; ++j) orow[j * 16] = q[j];
      }
    }
  } else {
#pragma unroll
    for (int i = 0; i < 4; ++i) {
#pragma unroll
      for (int j = 0; j < 4; ++j) {
#pragma unroll
        for (int r = 0; r < 4; ++r) {
          int gm = m0 + wr + i * 16 + quad * 4 + r;
          int gn = n0 + wc + j * 16 + lr;
          float h = bf16r(acc[i][j][r] + bias[gn]);
          float rr = bf16r(resid[(size_t)gm * N + gn]);
          ((float*)outp)[(size_t)gm * N + gn] = bf16r(rr + h);
        }
      }
    }
  }
  (void)M;
}

extern "C" void kernel_launch(void* const* d_in, const int* in_sizes, int n_in,
                              void* d_out, int out_size, void* d_ws, size_t ws_size,
                              hipStream_t stream) {
  const float* inputs = (const float*)d_in[0];  // [2,2048,2048]
  const float* ln_w   = (const float*)d_in[1];  // [2048]
  const float* ln_b   = (const float*)d_in[2];  // [2048]
  const float* W1     = (const float*)d_in[3];  // [8192,2048]
  const float* b1     = (const float*)d_in[4];  // [8192]
  const float* W2     = (const float*)d_in[5];  // [2048,8192]
  const float* b2     = (const float*)d_in[6];  // [2048]
  float* out = (float*)d_out;                   // [2,2048,2048] fp32 (bf16-valued)
  char* ws = (char*)d_ws;
  (void)in_sizes; (void)n_in; (void)out_size; (void)ws_size;

  // workspace layout (144 MiB total)
  unsigned short* qW1  = (unsigned short*)(ws);                      // 32 MiB
  unsigned short* qW2  = (unsigned short*)(ws + (size_t)33554432);   // 32 MiB
  unsigned short* a1   = (unsigned short*)(ws + (size_t)67108864);   // 16 MiB [4096,2048]
  unsigned short* act2 = (unsigned short*)(ws + (size_t)83886080);   // 64 MiB [4096,8192]

  const int M = 4096;

  // 1. merged prep: quantize W1+W2 and LN+quant the activations (one dispatch,
  //    512-thr blocks, 6144 blocks vs r0's 20480 -- latency/launch bound fix)
  prep_k<<<6144, 512, 0, stream>>>(W1, W2, inputs, ln_w, ln_b, qW1, qW2, a1);

  // 2. GEMM1 + bias + gelu + fused MX quant (DPP) -> quantized bf16 [4096,8192]
  gemm_mx<1><<<dim3(8192 / 128, M / 128), 256, 0, stream>>>(
      a1, qW1, M, 8192, 2048, b1, nullptr, (void*)act2);

  // 3. GEMM2 [4096,8192] x [2048,8192]^T + bias + residual -> fp32 out
  gemm_mx<2><<<dim3(2048 / 128, M / 128), 256, 0, stream>>>(
      act2, qW2, M, 2048, 8192, b2, inputs, (void*)out);
}